// Round 10
// baseline (245.587 us; speedup 1.0000x reference)
//
#include <hip/hip_runtime.h>

#define TPB 256

typedef __attribute__((ext_vector_type(8))) short bf16x8;
typedef __attribute__((ext_vector_type(4))) float f32x4;

__device__ __forceinline__ unsigned pack_bf16_rne(float lo, float hi) {
    union { float f; unsigned u; } a, b;
    a.f = lo; b.f = hi;
    unsigned ua = (a.u + 0x7fffu + ((a.u >> 16) & 1u)) >> 16;
    unsigned ub = (b.u + 0x7fffu + ((b.u >> 16) & 1u)) >> 16;
    return ua | (ub << 16);
}
__device__ __forceinline__ unsigned short bf16_rne1(float x) {
    union { float f; unsigned u; } a; a.f = x;
    return (unsigned short)((a.u + 0x7fffu + ((a.u >> 16) & 1u)) >> 16);
}
__device__ __forceinline__ float bf_lo(unsigned u) {
    union { unsigned i; float f; } c; c.i = u << 16; return c.f;
}
__device__ __forceinline__ float bf_hi(unsigned u) {
    union { unsigned i; float f; } c; c.i = u & 0xffff0000u; return c.f;
}

// ======================= sort-by-voxel pipeline =======================

__global__ __launch_bounds__(TPB) void zero_cnt(unsigned* __restrict__ cnt, int V) {
    const int i = blockIdx.x * TPB + threadIdx.x;
    if (i < V) cnt[i] = 0u;
}

__global__ __launch_bounds__(TPB) void hist_kernel(
    const int* __restrict__ vidx, unsigned* __restrict__ cnt, int N) {
    const int i = blockIdx.x * TPB + threadIdx.x;
    if (i < N) atomicAdd(&cnt[vidx[i]], 1u);
}

// single-block exclusive scan of cnt[V] -> offs[V]  (V ~ 100K)
#define SCAN_T 1024
__global__ __launch_bounds__(SCAN_T) void scan_kernel(
    const unsigned* __restrict__ cnt, unsigned* __restrict__ offs, int V) {
    __shared__ unsigned part[SCAN_T];
    const int t = threadIdx.x;
    const int chunk = (V + SCAN_T - 1) / SCAN_T;
    const int s = t * chunk;
    const int e = (s + chunk < V) ? s + chunk : V;

    unsigned sum = 0;
    for (int i = s; i < e; ++i) sum += cnt[i];
    part[t] = sum;
    __syncthreads();
    // Hillis-Steele inclusive scan over 1024 partials
    for (int d = 1; d < SCAN_T; d <<= 1) {
        unsigned v = (t >= d) ? part[t - d] : 0u;
        __syncthreads();
        part[t] += v;
        __syncthreads();
    }
    unsigned run = (t == 0) ? 0u : part[t - 1];   // exclusive prefix of this chunk
    for (int i = s; i < e; ++i) {
        offs[i] = run;
        run += cnt[i];
    }
}

// scatter: sorted[pos] = sample id, svox[pos] = voxel id (offs destroyed)
__global__ __launch_bounds__(TPB) void scatter_kernel(
    const int* __restrict__ vidx, unsigned* __restrict__ offs,
    int* __restrict__ sorted, int* __restrict__ svox, int N) {
    const int i = blockIdx.x * TPB + threadIdx.x;
    if (i < N) {
        const int v = vidx[i];
        const unsigned pos = atomicAdd(&offs[v], 1u);
        sorted[pos] = i;
        svox[pos]   = v;
    }
}

// ---- prep: valproj bf16 [K,64] = bf16(values) @ bf16(W) + b, via MFMA ----
// Bias folded into the table (sum of trilinear weights == 1).
// Block = 64 table rows (4 waves x 16-row tiles); C-frags staged through LDS
// so the global write is fully-coalesced uint4 rows.
__global__ __launch_bounds__(TPB) void proj_table_mfma(
    const float* __restrict__ values,   // [K,64] fp32
    const float* __restrict__ W,        // [64,64] fp32
    const float* __restrict__ b,        // [64]
    unsigned* __restrict__ vp,          // [K,32] u32 (=64 bf16) out
    int K)
{
    __shared__ unsigned short tile[64 * 64];   // [row_in_block][col]

    const int t    = threadIdx.x;
    const int l    = t & 63;
    const int w    = t >> 6;
    const int rb   = blockIdx.x * 64;
    const int r0   = rb + 16 * w;
    const int srow = l & 15;
    const int kq   = l >> 4;

    int row = r0 + srow;
    if (row >= K) row = K - 1;                   // clamped rows: LDS-only garbage

    bf16x8 af[2];
    #pragma unroll
    for (int kf = 0; kf < 2; ++kf) {
        const float4 x0 = *(const float4*)&values[(size_t)row * 64 + kf * 32 + 8 * kq];
        const float4 x1 = *(const float4*)&values[(size_t)row * 64 + kf * 32 + 8 * kq + 4];
        union { unsigned u[4]; bf16x8 v; } cv;
        cv.u[0] = pack_bf16_rne(x0.x, x0.y);
        cv.u[1] = pack_bf16_rne(x0.z, x0.w);
        cv.u[2] = pack_bf16_rne(x1.x, x1.y);
        cv.u[3] = pack_bf16_rne(x1.z, x1.w);
        af[kf] = cv.v;
    }

    #pragma unroll
    for (int ct = 0; ct < 4; ++ct) {
        const int col = ct * 16 + srow;
        const float bias = b[col];
        f32x4 acc;
        acc[0] = 0.f; acc[1] = 0.f; acc[2] = 0.f; acc[3] = 0.f;
        #pragma unroll
        for (int kf = 0; kf < 2; ++kf) {
            const int k0 = kf * 32 + 8 * kq;
            union { unsigned u[4]; bf16x8 v; } bv;   // B-frag inline from fp32 W (L1-hot)
            bv.u[0] = pack_bf16_rne(W[(k0 + 0) * 64 + col], W[(k0 + 1) * 64 + col]);
            bv.u[1] = pack_bf16_rne(W[(k0 + 2) * 64 + col], W[(k0 + 3) * 64 + col]);
            bv.u[2] = pack_bf16_rne(W[(k0 + 4) * 64 + col], W[(k0 + 5) * 64 + col]);
            bv.u[3] = pack_bf16_rne(W[(k0 + 6) * 64 + col], W[(k0 + 7) * 64 + col]);
            acc = __builtin_amdgcn_mfma_f32_16x16x32_bf16(af[kf], bv.v, acc, 0, 0, 0);
        }
        #pragma unroll
        for (int r = 0; r < 4; ++r)
            tile[(16 * w + 4 * kq + r) * 64 + col] = bf16_rne1(acc[r] + bias);
    }
    __syncthreads();

    {
        const int lrow = t >> 2;
        const int c    = t & 3;
        const int grow = rb + lrow;
        if (grow < K) {
            const uint4* src = (const uint4*)&tile[lrow * 64 + c * 16];
            uint4* dst = (uint4*)(vp + (size_t)grow * 32 + c * 8);
            dst[0] = src[0];
            dst[1] = src[1];
        }
    }
}

// ---- hot kernel: gather + trilinear weighted sum (bias pre-folded) ----
// Wave w owns 16 slots of the (sorted) sample list. Lane l: slot srow = l&15,
// dim octets 8*kq.. and 32+8*kq.. (kq = l>>4). Sorted order puts same-voxel
// samples in adjacent srow lanes -> identical corner rows merge in the
// coalescer. Output: 4 x 16B NT vector stores per lane (full 256B row per
// sample, scattered by original sample id).
__global__ __launch_bounds__(TPB) void gather_interp(
    const unsigned* __restrict__ vp,     // [K,32] u32 = 64 bf16 (128 B/row)
    const float* __restrict__ p,         // [N,3]
    const int*   __restrict__ feats,     // [V,8]
    const int*   __restrict__ vidx,      // [N]
    const int*   __restrict__ sorted,    // [N] or null
    const int*   __restrict__ svox,      // [N] or null
    float* __restrict__ out,             // [N,64]
    int N)
{
    const int t    = threadIdx.x;
    const int l    = t & 63;
    const int w    = t >> 6;
    const int base = blockIdx.x * 64 + 16 * w;
    const int srow = l & 15;
    const int kq   = l >> 4;

    const int  slot  = base + srow;
    const bool valid = slot < N;
    const int  cs    = valid ? slot : N - 1;

    int n, v;
    if (sorted) {
        n = sorted[cs];
        v = svox[cs];
    } else {
        n = cs;
        v = vidx[n];
    }

    // ---- corner indices + trilinear weights ----
    const int4 f0 = *(const int4*)&feats[(size_t)v * 8];
    const int4 f1 = *(const int4*)&feats[(size_t)v * 8 + 4];

    const float px = p[n * 3 + 0];
    const float py = p[n * 3 + 1];
    const float pz = p[n * 3 + 2];
    const float ox = 1.0f - px, oy = 1.0f - py, oz = 1.0f - pz;
    // corner order: [1,1,1],[1,1,0],[1,0,1],[0,1,1],[1,0,0],[0,1,0],[0,0,1],[0,0,0]
    float wgt[8];
    wgt[0] = px * py * pz;
    wgt[1] = px * py * oz;
    wgt[2] = px * oy * pz;
    wgt[3] = ox * py * pz;
    wgt[4] = px * oy * oz;
    wgt[5] = ox * py * oz;
    wgt[6] = ox * oy * pz;
    wgt[7] = ox * oy * oz;
    const int cidx[8] = {f0.x, f0.y, f0.z, f0.w, f1.x, f1.y, f1.z, f1.w};

    // ---- issue ALL 16 gathers (one vmcnt window, max MLP) ----
    uint4 q0s[8], q1s[8];
    #pragma unroll
    for (int c = 0; c < 8; ++c) {
        const unsigned* row = vp + (size_t)cidx[c] * 32;
        q0s[c] = *(const uint4*)(row + 4 * kq);        // dims 8kq .. 8kq+7
        q1s[c] = *(const uint4*)(row + 16 + 4 * kq);   // dims 32+8kq .. +7
    }

    // ---- weighted accumulate (fp32) ----
    float a0[8] = {0.f,0.f,0.f,0.f,0.f,0.f,0.f,0.f};
    float a1[8] = {0.f,0.f,0.f,0.f,0.f,0.f,0.f,0.f};
    #pragma unroll
    for (int c = 0; c < 8; ++c) {
        const uint4 q0 = q0s[c];
        const uint4 q1 = q1s[c];
        const float wc = wgt[c];
        a0[0] = fmaf(wc, bf_lo(q0.x), a0[0]);
        a0[1] = fmaf(wc, bf_hi(q0.x), a0[1]);
        a0[2] = fmaf(wc, bf_lo(q0.y), a0[2]);
        a0[3] = fmaf(wc, bf_hi(q0.y), a0[3]);
        a0[4] = fmaf(wc, bf_lo(q0.z), a0[4]);
        a0[5] = fmaf(wc, bf_hi(q0.z), a0[5]);
        a0[6] = fmaf(wc, bf_lo(q0.w), a0[6]);
        a0[7] = fmaf(wc, bf_hi(q0.w), a0[7]);
        a1[0] = fmaf(wc, bf_lo(q1.x), a1[0]);
        a1[1] = fmaf(wc, bf_hi(q1.x), a1[1]);
        a1[2] = fmaf(wc, bf_lo(q1.y), a1[2]);
        a1[3] = fmaf(wc, bf_hi(q1.y), a1[3]);
        a1[4] = fmaf(wc, bf_lo(q1.z), a1[4]);
        a1[5] = fmaf(wc, bf_hi(q1.z), a1[5]);
        a1[6] = fmaf(wc, bf_lo(q1.w), a1[6]);
        a1[7] = fmaf(wc, bf_hi(q1.w), a1[7]);
    }

    // ---- store (4 x f32x4 NT vector stores; full 256B row per sample) ----
    if (valid) {
        f32x4* o4 = (f32x4*)(out + (size_t)n * 64);
        f32x4 v0, v1, v2, v3;
        v0[0] = a0[0]; v0[1] = a0[1]; v0[2] = a0[2]; v0[3] = a0[3];
        v1[0] = a0[4]; v1[1] = a0[5]; v1[2] = a0[6]; v1[3] = a0[7];
        v2[0] = a1[0]; v2[1] = a1[1]; v2[2] = a1[2]; v2[3] = a1[3];
        v3[0] = a1[4]; v3[1] = a1[5]; v3[2] = a1[6]; v3[3] = a1[7];
        __builtin_nontemporal_store(v0, o4 + 2 * kq);
        __builtin_nontemporal_store(v1, o4 + 2 * kq + 1);
        __builtin_nontemporal_store(v2, o4 + 8 + 2 * kq);
        __builtin_nontemporal_store(v3, o4 + 8 + 2 * kq + 1);
    }
}

// ---- fallback: proven round-2 fp32 kernel (used only if ws too small) ----
__global__ __launch_bounds__(TPB) void fused_embed_proj_fp32(
    const float* __restrict__ values, const float* __restrict__ p,
    const float* __restrict__ W, const float* __restrict__ b,
    const int* __restrict__ feats, const int* __restrict__ vidx,
    float* __restrict__ out, int N)
{
    __shared__ float featS[64][68];
    __shared__ float Wlds[64][64];

    const int t    = threadIdx.x;
    const int base = blockIdx.x * 64;
    {
        const float4* Wv = (const float4*)W;
        float4*       Wl = (float4*)&Wlds[0][0];
        #pragma unroll
        for (int i = 0; i < 4; ++i) Wl[t + i * TPB] = Wv[t + i * TPB];
    }
    const int g  = t & 15;
    const int sb = t >> 4;

    int   cidx[4][8];
    float wgt[4][8];
    #pragma unroll
    for (int i = 0; i < 4; ++i) {
        const int s = sb + 16 * i;
        int n = base + s;
        if (n >= N) n = N - 1;
        const int v = vidx[n];
        const int4 f0 = *(const int4*)&feats[(size_t)v * 8];
        const int4 f1 = *(const int4*)&feats[(size_t)v * 8 + 4];
        cidx[i][0] = f0.x; cidx[i][1] = f0.y; cidx[i][2] = f0.z; cidx[i][3] = f0.w;
        cidx[i][4] = f1.x; cidx[i][5] = f1.y; cidx[i][6] = f1.z; cidx[i][7] = f1.w;
        const float px = p[n * 3], py = p[n * 3 + 1], pz = p[n * 3 + 2];
        const float ox = 1.f - px, oy = 1.f - py, oz = 1.f - pz;
        wgt[i][0] = px * py * pz; wgt[i][1] = px * py * oz;
        wgt[i][2] = px * oy * pz; wgt[i][3] = ox * py * pz;
        wgt[i][4] = px * oy * oz; wgt[i][5] = ox * py * oz;
        wgt[i][6] = ox * oy * pz; wgt[i][7] = ox * oy * oz;
    }
    #pragma unroll
    for (int i = 0; i < 4; ++i) {
        float4 acc; acc.x = acc.y = acc.z = acc.w = 0.f;
        #pragma unroll
        for (int c = 0; c < 8; ++c) {
            const float4 val = *(const float4*)&values[(size_t)cidx[i][c] * 64 + 4 * g];
            const float w = wgt[i][c];
            acc.x = fmaf(w, val.x, acc.x); acc.y = fmaf(w, val.y, acc.y);
            acc.z = fmaf(w, val.z, acc.z); acc.w = fmaf(w, val.w, acc.w);
        }
        *(float4*)&featS[sb + 16 * i][4 * g] = acc;
    }
    __syncthreads();

    const int tx = t & 15, ty = t >> 4;
    float acc[4][4];
    {
        const float4 bb = ((const float4*)b)[tx];
        #pragma unroll
        for (int j = 0; j < 4; ++j) {
            acc[j][0] = bb.x; acc[j][1] = bb.y; acc[j][2] = bb.z; acc[j][3] = bb.w;
        }
    }
    #pragma unroll 4
    for (int d = 0; d < 64; ++d) {
        const float a0 = featS[4 * ty + 0][d];
        const float a1 = featS[4 * ty + 1][d];
        const float a2 = featS[4 * ty + 2][d];
        const float a3 = featS[4 * ty + 3][d];
        const float4 wr = *(const float4*)&Wlds[d][4 * tx];
        acc[0][0] = fmaf(a0, wr.x, acc[0][0]); acc[0][1] = fmaf(a0, wr.y, acc[0][1]);
        acc[0][2] = fmaf(a0, wr.z, acc[0][2]); acc[0][3] = fmaf(a0, wr.w, acc[0][3]);
        acc[1][0] = fmaf(a1, wr.x, acc[1][0]); acc[1][1] = fmaf(a1, wr.y, acc[1][1]);
        acc[1][2] = fmaf(a1, wr.z, acc[1][2]); acc[1][3] = fmaf(a1, wr.w, acc[1][3]);
        acc[2][0] = fmaf(a2, wr.x, acc[2][0]); acc[2][1] = fmaf(a2, wr.y, acc[2][1]);
        acc[2][2] = fmaf(a2, wr.z, acc[2][2]); acc[2][3] = fmaf(a2, wr.w, acc[2][3]);
        acc[3][0] = fmaf(a3, wr.x, acc[3][0]); acc[3][1] = fmaf(a3, wr.y, acc[3][1]);
        acc[3][2] = fmaf(a3, wr.z, acc[3][2]); acc[3][3] = fmaf(a3, wr.w, acc[3][3]);
    }
    #pragma unroll
    for (int j = 0; j < 4; ++j) {
        const int n = base + 4 * ty + j;
        if (n < N) {
            float4 o; o.x = acc[j][0]; o.y = acc[j][1]; o.z = acc[j][2]; o.w = acc[j][3];
            *(float4*)&out[(size_t)n * 64 + 4 * tx] = o;
        }
    }
}

extern "C" void kernel_launch(void* const* d_in, const int* in_sizes, int n_in,
                              void* d_out, int out_size, void* d_ws, size_t ws_size,
                              hipStream_t stream) {
    const float* values = (const float*)d_in[0];
    const float* p      = (const float*)d_in[1];
    const float* W      = (const float*)d_in[2];
    const float* b      = (const float*)d_in[3];
    const int*   feats  = (const int*)d_in[4];
    const int*   vidx   = (const int*)d_in[5];
    float* out = (float*)d_out;

    const int N  = in_sizes[5];
    const int KD = in_sizes[0];            // K * 64
    const int K  = KD / 64;
    const int V  = in_sizes[4] / 8;
    const int nblocks = (N + 63) / 64;

    // ws layout: vp | cnt | offs | sorted | svox (256B-aligned)
    auto align256 = [](size_t x) { return (x + 255) & ~(size_t)255; };
    const size_t vp_off     = 0;
    const size_t vp_bytes   = align256((size_t)KD * 2);
    const size_t cnt_off    = vp_bytes;
    const size_t cnt_bytes  = align256((size_t)V * 4);
    const size_t offs_off   = cnt_off + cnt_bytes;
    const size_t sorted_off = offs_off + cnt_bytes;
    const size_t svox_off   = sorted_off + align256((size_t)N * 4);
    const size_t need_sort  = svox_off + align256((size_t)N * 4);
    const size_t need_vp    = (size_t)KD * 2;

    if (ws_size >= need_sort) {
        unsigned* vp     = (unsigned*)((char*)d_ws + vp_off);
        unsigned* cnt    = (unsigned*)((char*)d_ws + cnt_off);
        unsigned* offs   = (unsigned*)((char*)d_ws + offs_off);
        int*      sorted = (int*)((char*)d_ws + sorted_off);
        int*      svox   = (int*)((char*)d_ws + svox_off);

        zero_cnt<<<(V + TPB - 1) / TPB, TPB, 0, stream>>>(cnt, V);
        hist_kernel<<<(N + TPB - 1) / TPB, TPB, 0, stream>>>(vidx, cnt, N);
        scan_kernel<<<1, SCAN_T, 0, stream>>>(cnt, offs, V);
        scatter_kernel<<<(N + TPB - 1) / TPB, TPB, 0, stream>>>(vidx, offs, sorted, svox, N);
        proj_table_mfma<<<(K + 63) / 64, TPB, 0, stream>>>(values, W, b, vp, K);
        gather_interp<<<nblocks, TPB, 0, stream>>>(
            vp, p, feats, vidx, sorted, svox, out, N);
    } else if (ws_size >= need_vp) {
        unsigned* vp = (unsigned*)d_ws;
        proj_table_mfma<<<(K + 63) / 64, TPB, 0, stream>>>(values, W, b, vp, K);
        gather_interp<<<nblocks, TPB, 0, stream>>>(
            vp, p, feats, vidx, nullptr, nullptr, out, N);
    } else {
        fused_embed_proj_fp32<<<nblocks, TPB, 0, stream>>>(
            values, p, W, b, feats, vidx, out, N);
    }
}

// Round 11
// 93.911 us; speedup vs baseline: 2.6151x; 2.6151x over previous
//
#include <hip/hip_runtime.h>

#define TPB 256

typedef __attribute__((ext_vector_type(8))) short bf16x8;
typedef __attribute__((ext_vector_type(4))) float f32x4;

__device__ __forceinline__ unsigned pack_bf16_rne(float lo, float hi) {
    union { float f; unsigned u; } a, b;
    a.f = lo; b.f = hi;
    unsigned ua = (a.u + 0x7fffu + ((a.u >> 16) & 1u)) >> 16;
    unsigned ub = (b.u + 0x7fffu + ((b.u >> 16) & 1u)) >> 16;
    return ua | (ub << 16);
}
__device__ __forceinline__ unsigned short bf16_rne1(float x) {
    union { float f; unsigned u; } a; a.f = x;
    return (unsigned short)((a.u + 0x7fffu + ((a.u >> 16) & 1u)) >> 16);
}
__device__ __forceinline__ float bf_lo(unsigned u) {
    union { unsigned i; float f; } c; c.i = u << 16; return c.f;
}
__device__ __forceinline__ float bf_hi(unsigned u) {
    union { unsigned i; float f; } c; c.i = u & 0xffff0000u; return c.f;
}

// ======================= sort-by-voxel pipeline =======================

__global__ __launch_bounds__(TPB) void zero_cnt(unsigned* __restrict__ cnt, int V) {
    const int i = blockIdx.x * TPB + threadIdx.x;
    if (i < V) cnt[i] = 0u;
}

__global__ __launch_bounds__(TPB) void hist_kernel(
    const int* __restrict__ vidx, unsigned* __restrict__ cnt, int N) {
    const int i = blockIdx.x * TPB + threadIdx.x;
    if (i < N) atomicAdd(&cnt[vidx[i]], 1u);
}

// scan1: per-2048-chunk local exclusive prefixes + chunk totals.
// grid = ceil(V/2048), 256 threads, 8 elements/thread.
__global__ __launch_bounds__(TPB) void scan1_kernel(
    const unsigned* __restrict__ cnt, unsigned* __restrict__ loc,
    unsigned* __restrict__ chunksum, int V)
{
    __shared__ unsigned part[TPB];
    const int t    = threadIdx.x;
    const int base = blockIdx.x * 2048 + t * 8;

    unsigned e[8];
    unsigned s = 0;
    #pragma unroll
    for (int j = 0; j < 8; ++j) {
        e[j] = (base + j < V) ? cnt[base + j] : 0u;
        s += e[j];
    }
    part[t] = s;
    __syncthreads();
    #pragma unroll
    for (int d = 1; d < TPB; d <<= 1) {
        unsigned v = (t >= d) ? part[t - d] : 0u;
        __syncthreads();
        part[t] += v;
        __syncthreads();
    }
    unsigned run = part[t] - s;          // exclusive prefix of this thread's span
    #pragma unroll
    for (int j = 0; j < 8; ++j) {
        if (base + j < V) loc[base + j] = run;
        run += e[j];
    }
    if (t == TPB - 1) chunksum[blockIdx.x] = part[TPB - 1];
}

// scan2: exclusive scan of chunk totals (nchunks <= 256), one block.
__global__ __launch_bounds__(TPB) void scan2_kernel(
    unsigned* __restrict__ chunksum, unsigned* __restrict__ chunkpref, int nc)
{
    __shared__ unsigned part[TPB];
    const int t = threadIdx.x;
    unsigned s = (t < nc) ? chunksum[t] : 0u;
    part[t] = s;
    __syncthreads();
    #pragma unroll
    for (int d = 1; d < TPB; d <<= 1) {
        unsigned v = (t >= d) ? part[t - d] : 0u;
        __syncthreads();
        part[t] += v;
        __syncthreads();
    }
    if (t < nc) chunkpref[t] = part[t] - s;
}

// scatter: pos = chunkpref[v>>11] + atomicAdd(&loc[v],1)
__global__ __launch_bounds__(TPB) void scatter_kernel(
    const int* __restrict__ vidx, unsigned* __restrict__ loc,
    const unsigned* __restrict__ chunkpref,
    int* __restrict__ sorted, int* __restrict__ svox, int N)
{
    const int i = blockIdx.x * TPB + threadIdx.x;
    if (i < N) {
        const int v = vidx[i];
        const unsigned pos = chunkpref[v >> 11] + atomicAdd(&loc[v], 1u);
        sorted[pos] = i;
        svox[pos]   = v;
    }
}

// ---- prep: valproj bf16 [K,64] = bf16(values) @ bf16(W) + b, via MFMA ----
// Bias folded into the table (sum of trilinear weights == 1).
__global__ __launch_bounds__(TPB) void proj_table_mfma(
    const float* __restrict__ values,   // [K,64] fp32
    const float* __restrict__ W,        // [64,64] fp32
    const float* __restrict__ b,        // [64]
    unsigned* __restrict__ vp,          // [K,32] u32 (=64 bf16) out
    int K)
{
    __shared__ unsigned short tile[64 * 64];   // [row_in_block][col]

    const int t    = threadIdx.x;
    const int l    = t & 63;
    const int w    = t >> 6;
    const int rb   = blockIdx.x * 64;
    const int r0   = rb + 16 * w;
    const int srow = l & 15;
    const int kq   = l >> 4;

    int row = r0 + srow;
    if (row >= K) row = K - 1;                   // clamped rows: LDS-only garbage

    bf16x8 af[2];
    #pragma unroll
    for (int kf = 0; kf < 2; ++kf) {
        const float4 x0 = *(const float4*)&values[(size_t)row * 64 + kf * 32 + 8 * kq];
        const float4 x1 = *(const float4*)&values[(size_t)row * 64 + kf * 32 + 8 * kq + 4];
        union { unsigned u[4]; bf16x8 v; } cv;
        cv.u[0] = pack_bf16_rne(x0.x, x0.y);
        cv.u[1] = pack_bf16_rne(x0.z, x0.w);
        cv.u[2] = pack_bf16_rne(x1.x, x1.y);
        cv.u[3] = pack_bf16_rne(x1.z, x1.w);
        af[kf] = cv.v;
    }

    #pragma unroll
    for (int ct = 0; ct < 4; ++ct) {
        const int col = ct * 16 + srow;
        const float bias = b[col];
        f32x4 acc;
        acc[0] = 0.f; acc[1] = 0.f; acc[2] = 0.f; acc[3] = 0.f;
        #pragma unroll
        for (int kf = 0; kf < 2; ++kf) {
            const int k0 = kf * 32 + 8 * kq;
            union { unsigned u[4]; bf16x8 v; } bv;
            bv.u[0] = pack_bf16_rne(W[(k0 + 0) * 64 + col], W[(k0 + 1) * 64 + col]);
            bv.u[1] = pack_bf16_rne(W[(k0 + 2) * 64 + col], W[(k0 + 3) * 64 + col]);
            bv.u[2] = pack_bf16_rne(W[(k0 + 4) * 64 + col], W[(k0 + 5) * 64 + col]);
            bv.u[3] = pack_bf16_rne(W[(k0 + 6) * 64 + col], W[(k0 + 7) * 64 + col]);
            acc = __builtin_amdgcn_mfma_f32_16x16x32_bf16(af[kf], bv.v, acc, 0, 0, 0);
        }
        #pragma unroll
        for (int r = 0; r < 4; ++r)
            tile[(16 * w + 4 * kq + r) * 64 + col] = bf16_rne1(acc[r] + bias);
    }
    __syncthreads();

    {
        const int lrow = t >> 2;
        const int c    = t & 3;
        const int grow = rb + lrow;
        if (grow < K) {
            const uint4* src = (const uint4*)&tile[lrow * 64 + c * 16];
            uint4* dst = (uint4*)(vp + (size_t)grow * 32 + c * 8);
            dst[0] = src[0];
            dst[1] = src[1];
        }
    }
}

// ---- hot kernel: gather + trilinear weighted sum (bias pre-folded) ----
__global__ __launch_bounds__(TPB) void gather_interp(
    const unsigned* __restrict__ vp,     // [K,32] u32 = 64 bf16 (128 B/row)
    const float* __restrict__ p,         // [N,3]
    const int*   __restrict__ feats,     // [V,8]
    const int*   __restrict__ vidx,      // [N]
    const int*   __restrict__ sorted,    // [N] or null
    const int*   __restrict__ svox,      // [N] or null
    float* __restrict__ out,             // [N,64]
    int N)
{
    const int t    = threadIdx.x;
    const int l    = t & 63;
    const int w    = t >> 6;
    const int base = blockIdx.x * 64 + 16 * w;
    const int srow = l & 15;
    const int kq   = l >> 4;

    const int  slot  = base + srow;
    const bool valid = slot < N;
    const int  cs    = valid ? slot : N - 1;

    int n, v;
    if (sorted) {
        n = sorted[cs];
        v = svox[cs];
    } else {
        n = cs;
        v = vidx[n];
    }

    const int4 f0 = *(const int4*)&feats[(size_t)v * 8];
    const int4 f1 = *(const int4*)&feats[(size_t)v * 8 + 4];

    const float px = p[n * 3 + 0];
    const float py = p[n * 3 + 1];
    const float pz = p[n * 3 + 2];
    const float ox = 1.0f - px, oy = 1.0f - py, oz = 1.0f - pz;
    // corner order: [1,1,1],[1,1,0],[1,0,1],[0,1,1],[1,0,0],[0,1,0],[0,0,1],[0,0,0]
    float wgt[8];
    wgt[0] = px * py * pz;
    wgt[1] = px * py * oz;
    wgt[2] = px * oy * pz;
    wgt[3] = ox * py * pz;
    wgt[4] = px * oy * oz;
    wgt[5] = ox * py * oz;
    wgt[6] = ox * oy * pz;
    wgt[7] = ox * oy * oz;
    const int cidx[8] = {f0.x, f0.y, f0.z, f0.w, f1.x, f1.y, f1.z, f1.w};

    uint4 q0s[8], q1s[8];
    #pragma unroll
    for (int c = 0; c < 8; ++c) {
        const unsigned* row = vp + (size_t)cidx[c] * 32;
        q0s[c] = *(const uint4*)(row + 4 * kq);
        q1s[c] = *(const uint4*)(row + 16 + 4 * kq);
    }

    float a0[8] = {0.f,0.f,0.f,0.f,0.f,0.f,0.f,0.f};
    float a1[8] = {0.f,0.f,0.f,0.f,0.f,0.f,0.f,0.f};
    #pragma unroll
    for (int c = 0; c < 8; ++c) {
        const uint4 q0 = q0s[c];
        const uint4 q1 = q1s[c];
        const float wc = wgt[c];
        a0[0] = fmaf(wc, bf_lo(q0.x), a0[0]);
        a0[1] = fmaf(wc, bf_hi(q0.x), a0[1]);
        a0[2] = fmaf(wc, bf_lo(q0.y), a0[2]);
        a0[3] = fmaf(wc, bf_hi(q0.y), a0[3]);
        a0[4] = fmaf(wc, bf_lo(q0.z), a0[4]);
        a0[5] = fmaf(wc, bf_hi(q0.z), a0[5]);
        a0[6] = fmaf(wc, bf_lo(q0.w), a0[6]);
        a0[7] = fmaf(wc, bf_hi(q0.w), a0[7]);
        a1[0] = fmaf(wc, bf_lo(q1.x), a1[0]);
        a1[1] = fmaf(wc, bf_hi(q1.x), a1[1]);
        a1[2] = fmaf(wc, bf_lo(q1.y), a1[2]);
        a1[3] = fmaf(wc, bf_hi(q1.y), a1[3]);
        a1[4] = fmaf(wc, bf_lo(q1.z), a1[4]);
        a1[5] = fmaf(wc, bf_hi(q1.z), a1[5]);
        a1[6] = fmaf(wc, bf_lo(q1.w), a1[6]);
        a1[7] = fmaf(wc, bf_hi(q1.w), a1[7]);
    }

    if (valid) {
        f32x4* o4 = (f32x4*)(out + (size_t)n * 64);
        f32x4 v0, v1, v2, v3;
        v0[0] = a0[0]; v0[1] = a0[1]; v0[2] = a0[2]; v0[3] = a0[3];
        v1[0] = a0[4]; v1[1] = a0[5]; v1[2] = a0[6]; v1[3] = a0[7];
        v2[0] = a1[0]; v2[1] = a1[1]; v2[2] = a1[2]; v2[3] = a1[3];
        v3[0] = a1[4]; v3[1] = a1[5]; v3[2] = a1[6]; v3[3] = a1[7];
        __builtin_nontemporal_store(v0, o4 + 2 * kq);
        __builtin_nontemporal_store(v1, o4 + 2 * kq + 1);
        __builtin_nontemporal_store(v2, o4 + 8 + 2 * kq);
        __builtin_nontemporal_store(v3, o4 + 8 + 2 * kq + 1);
    }
}

// ---- fallback: proven round-2 fp32 kernel (used only if ws too small) ----
__global__ __launch_bounds__(TPB) void fused_embed_proj_fp32(
    const float* __restrict__ values, const float* __restrict__ p,
    const float* __restrict__ W, const float* __restrict__ b,
    const int* __restrict__ feats, const int* __restrict__ vidx,
    float* __restrict__ out, int N)
{
    __shared__ float featS[64][68];
    __shared__ float Wlds[64][64];

    const int t    = threadIdx.x;
    const int base = blockIdx.x * 64;
    {
        const float4* Wv = (const float4*)W;
        float4*       Wl = (float4*)&Wlds[0][0];
        #pragma unroll
        for (int i = 0; i < 4; ++i) Wl[t + i * TPB] = Wv[t + i * TPB];
    }
    const int g  = t & 15;
    const int sb = t >> 4;

    int   cidx[4][8];
    float wgt[4][8];
    #pragma unroll
    for (int i = 0; i < 4; ++i) {
        const int s = sb + 16 * i;
        int n = base + s;
        if (n >= N) n = N - 1;
        const int v = vidx[n];
        const int4 f0 = *(const int4*)&feats[(size_t)v * 8];
        const int4 f1 = *(const int4*)&feats[(size_t)v * 8 + 4];
        cidx[i][0] = f0.x; cidx[i][1] = f0.y; cidx[i][2] = f0.z; cidx[i][3] = f0.w;
        cidx[i][4] = f1.x; cidx[i][5] = f1.y; cidx[i][6] = f1.z; cidx[i][7] = f1.w;
        const float px = p[n * 3], py = p[n * 3 + 1], pz = p[n * 3 + 2];
        const float ox = 1.f - px, oy = 1.f - py, oz = 1.f - pz;
        wgt[i][0] = px * py * pz; wgt[i][1] = px * py * oz;
        wgt[i][2] = px * oy * pz; wgt[i][3] = ox * py * pz;
        wgt[i][4] = px * oy * oz; wgt[i][5] = ox * py * oz;
        wgt[i][6] = ox * oy * pz; wgt[i][7] = ox * oy * oz;
    }
    #pragma unroll
    for (int i = 0; i < 4; ++i) {
        float4 acc; acc.x = acc.y = acc.z = acc.w = 0.f;
        #pragma unroll
        for (int c = 0; c < 8; ++c) {
            const float4 val = *(const float4*)&values[(size_t)cidx[i][c] * 64 + 4 * g];
            const float w = wgt[i][c];
            acc.x = fmaf(w, val.x, acc.x); acc.y = fmaf(w, val.y, acc.y);
            acc.z = fmaf(w, val.z, acc.z); acc.w = fmaf(w, val.w, acc.w);
        }
        *(float4*)&featS[sb + 16 * i][4 * g] = acc;
    }
    __syncthreads();

    const int tx = t & 15, ty = t >> 4;
    float acc[4][4];
    {
        const float4 bb = ((const float4*)b)[tx];
        #pragma unroll
        for (int j = 0; j < 4; ++j) {
            acc[j][0] = bb.x; acc[j][1] = bb.y; acc[j][2] = bb.z; acc[j][3] = bb.w;
        }
    }
    #pragma unroll 4
    for (int d = 0; d < 64; ++d) {
        const float a0 = featS[4 * ty + 0][d];
        const float a1 = featS[4 * ty + 1][d];
        const float a2 = featS[4 * ty + 2][d];
        const float a3 = featS[4 * ty + 3][d];
        const float4 wr = *(const float4*)&Wlds[d][4 * tx];
        acc[0][0] = fmaf(a0, wr.x, acc[0][0]); acc[0][1] = fmaf(a0, wr.y, acc[0][1]);
        acc[0][2] = fmaf(a0, wr.z, acc[0][2]); acc[0][3] = fmaf(a0, wr.w, acc[0][3]);
        acc[1][0] = fmaf(a1, wr.x, acc[1][0]); acc[1][1] = fmaf(a1, wr.y, acc[1][1]);
        acc[1][2] = fmaf(a1, wr.z, acc[1][2]); acc[1][3] = fmaf(a1, wr.w, acc[1][3]);
        acc[2][0] = fmaf(a2, wr.x, acc[2][0]); acc[2][1] = fmaf(a2, wr.y, acc[2][1]);
        acc[2][2] = fmaf(a2, wr.z, acc[2][2]); acc[2][3] = fmaf(a2, wr.w, acc[2][3]);
        acc[3][0] = fmaf(a3, wr.x, acc[3][0]); acc[3][1] = fmaf(a3, wr.y, acc[3][1]);
        acc[3][2] = fmaf(a3, wr.z, acc[3][2]); acc[3][3] = fmaf(a3, wr.w, acc[3][3]);
    }
    #pragma unroll
    for (int j = 0; j < 4; ++j) {
        const int n = base + 4 * ty + j;
        if (n < N) {
            float4 o; o.x = acc[j][0]; o.y = acc[j][1]; o.z = acc[j][2]; o.w = acc[j][3];
            *(float4*)&out[(size_t)n * 64 + 4 * tx] = o;
        }
    }
}

extern "C" void kernel_launch(void* const* d_in, const int* in_sizes, int n_in,
                              void* d_out, int out_size, void* d_ws, size_t ws_size,
                              hipStream_t stream) {
    const float* values = (const float*)d_in[0];
    const float* p      = (const float*)d_in[1];
    const float* W      = (const float*)d_in[2];
    const float* b      = (const float*)d_in[3];
    const int*   feats  = (const int*)d_in[4];
    const int*   vidx   = (const int*)d_in[5];
    float* out = (float*)d_out;

    const int N  = in_sizes[5];
    const int KD = in_sizes[0];            // K * 64
    const int K  = KD / 64;
    const int V  = in_sizes[4] / 8;
    const int nblocks = (N + 63) / 64;
    const int nchunks = (V + 2047) / 2048; // <= 256 for V <= 512K

    // ws layout: vp | cnt | loc | sorted | svox | chunksum | chunkpref
    auto align256 = [](size_t x) { return (x + 255) & ~(size_t)255; };
    const size_t vp_off     = 0;
    const size_t vp_bytes   = align256((size_t)KD * 2);
    const size_t cnt_off    = vp_bytes;
    const size_t cnt_bytes  = align256((size_t)V * 4);
    const size_t loc_off    = cnt_off + cnt_bytes;
    const size_t sorted_off = loc_off + cnt_bytes;
    const size_t svox_off   = sorted_off + align256((size_t)N * 4);
    const size_t csum_off   = svox_off + align256((size_t)N * 4);
    const size_t cpref_off  = csum_off + align256((size_t)nchunks * 4);
    const size_t need_sort  = cpref_off + align256((size_t)nchunks * 4);
    const size_t need_vp    = (size_t)KD * 2;

    if (ws_size >= need_sort && nchunks <= TPB) {
        unsigned* vp     = (unsigned*)((char*)d_ws + vp_off);
        unsigned* cnt    = (unsigned*)((char*)d_ws + cnt_off);
        unsigned* loc    = (unsigned*)((char*)d_ws + loc_off);
        int*      sorted = (int*)((char*)d_ws + sorted_off);
        int*      svox   = (int*)((char*)d_ws + svox_off);
        unsigned* csum   = (unsigned*)((char*)d_ws + csum_off);
        unsigned* cpref  = (unsigned*)((char*)d_ws + cpref_off);

        zero_cnt<<<(V + TPB - 1) / TPB, TPB, 0, stream>>>(cnt, V);
        hist_kernel<<<(N + TPB - 1) / TPB, TPB, 0, stream>>>(vidx, cnt, N);
        scan1_kernel<<<nchunks, TPB, 0, stream>>>(cnt, loc, csum, V);
        scan2_kernel<<<1, TPB, 0, stream>>>(csum, cpref, nchunks);
        scatter_kernel<<<(N + TPB - 1) / TPB, TPB, 0, stream>>>(
            vidx, loc, cpref, sorted, svox, N);
        proj_table_mfma<<<(K + 63) / 64, TPB, 0, stream>>>(values, W, b, vp, K);
        gather_interp<<<nblocks, TPB, 0, stream>>>(
            vp, p, feats, vidx, sorted, svox, out, N);
    } else if (ws_size >= need_vp) {
        unsigned* vp = (unsigned*)d_ws;
        proj_table_mfma<<<(K + 63) / 64, TPB, 0, stream>>>(values, W, b, vp, K);
        gather_interp<<<nblocks, TPB, 0, stream>>>(
            vp, p, feats, vidx, nullptr, nullptr, out, N);
    } else {
        fused_embed_proj_fp32<<<nblocks, TPB, 0, stream>>>(
            values, p, W, b, feats, vidx, out, N);
    }
}

// Round 12
// 81.656 us; speedup vs baseline: 3.0076x; 1.1501x over previous
//
#include <hip/hip_runtime.h>

#define TPB 256

typedef __attribute__((ext_vector_type(8))) short bf16x8;
typedef __attribute__((ext_vector_type(4))) float f32x4;

__device__ __forceinline__ unsigned pack_bf16_rne(float lo, float hi) {
    union { float f; unsigned u; } a, b;
    a.f = lo; b.f = hi;
    unsigned ua = (a.u + 0x7fffu + ((a.u >> 16) & 1u)) >> 16;
    unsigned ub = (b.u + 0x7fffu + ((b.u >> 16) & 1u)) >> 16;
    return ua | (ub << 16);
}
__device__ __forceinline__ float bf_lo(unsigned u) {
    union { unsigned i; float f; } c; c.i = u << 16; return c.f;
}
__device__ __forceinline__ float bf_hi(unsigned u) {
    union { unsigned i; float f; } c; c.i = u & 0xffff0000u; return c.f;
}

// ---- L1: fused prep: cvt values->bf16 | zero cnt | W MFMA B-fragments ----
// blocks [0,nvb): cvt; [nvb,nvb+zb): zero; last block: W frags.
__global__ __launch_bounds__(TPB) void prep_combo(
    const float4* __restrict__ src, uint4* __restrict__ dst, int n8, int nvb,
    unsigned* __restrict__ cnt, int V, int zb,
    const float* __restrict__ W, uint4* __restrict__ wfrag)
{
    int bid = blockIdx.x;
    if (bid < nvb) {
        const int i = bid * TPB + threadIdx.x;
        if (i < n8) {
            const float4 a = src[2 * i];
            const float4 b = src[2 * i + 1];
            uint4 o;
            o.x = pack_bf16_rne(a.x, a.y);
            o.y = pack_bf16_rne(a.z, a.w);
            o.z = pack_bf16_rne(b.x, b.y);
            o.w = pack_bf16_rne(b.z, b.w);
            dst[i] = o;
        }
        return;
    }
    bid -= nvb;
    if (bid < zb) {
        const int i = bid * TPB + threadIdx.x;
        if (i < V) cnt[i] = 0u;
        return;
    }
    // W fragments: frag f = ct*2+kf, lane l, elem j = W[kf*32+8*(l>>4)+j][ct*16+(l&15)]
    const int t = threadIdx.x;
    for (int e = t; e < 512; e += TPB) {
        const int l  = e & 63;
        const int f  = e >> 6;
        const int ct = f >> 1;
        const int kf = f & 1;
        const int col = ct * 16 + (l & 15);
        const int k0  = kf * 32 + 8 * (l >> 4);
        uint4 o;
        o.x = pack_bf16_rne(W[(k0 + 0) * 64 + col], W[(k0 + 1) * 64 + col]);
        o.y = pack_bf16_rne(W[(k0 + 2) * 64 + col], W[(k0 + 3) * 64 + col]);
        o.z = pack_bf16_rne(W[(k0 + 4) * 64 + col], W[(k0 + 5) * 64 + col]);
        o.w = pack_bf16_rne(W[(k0 + 6) * 64 + col], W[(k0 + 7) * 64 + col]);
        wfrag[e] = o;
    }
}

__global__ __launch_bounds__(TPB) void hist_kernel(
    const int* __restrict__ vidx, unsigned* __restrict__ cnt, int N) {
    const int i = blockIdx.x * TPB + threadIdx.x;
    if (i < N) atomicAdd(&cnt[vidx[i]], 1u);
}

// scan1: per-2048-chunk local exclusive prefixes + chunk totals
__global__ __launch_bounds__(TPB) void scan1_kernel(
    const unsigned* __restrict__ cnt, unsigned* __restrict__ loc,
    unsigned* __restrict__ chunksum, int V)
{
    __shared__ unsigned part[TPB];
    const int t    = threadIdx.x;
    const int base = blockIdx.x * 2048 + t * 8;

    unsigned e[8];
    unsigned s = 0;
    #pragma unroll
    for (int j = 0; j < 8; ++j) {
        e[j] = (base + j < V) ? cnt[base + j] : 0u;
        s += e[j];
    }
    part[t] = s;
    __syncthreads();
    for (int d = 1; d < TPB; d <<= 1) {
        unsigned v = (t >= d) ? part[t - d] : 0u;
        __syncthreads();
        part[t] += v;
        __syncthreads();
    }
    unsigned run = part[t] - s;
    #pragma unroll
    for (int j = 0; j < 8; ++j) {
        if (base + j < V) loc[base + j] = run;
        run += e[j];
    }
    if (t == TPB - 1) chunksum[blockIdx.x] = part[TPB - 1];
}

// scan2: exclusive scan of chunk totals (nc <= 256)
__global__ __launch_bounds__(TPB) void scan2_kernel(
    const unsigned* __restrict__ chunksum, unsigned* __restrict__ chunkpref, int nc)
{
    __shared__ unsigned part[TPB];
    const int t = threadIdx.x;
    unsigned s = (t < nc) ? chunksum[t] : 0u;
    part[t] = s;
    __syncthreads();
    for (int d = 1; d < TPB; d <<= 1) {
        unsigned v = (t >= d) ? part[t - d] : 0u;
        __syncthreads();
        part[t] += v;
        __syncthreads();
    }
    if (t < nc) chunkpref[t] = part[t] - s;
}

// scatter: psort[pos] = {px,py,pz,bitcast(n)}, svox[pos] = v
__global__ __launch_bounds__(TPB) void scatter_kernel(
    const int* __restrict__ vidx, const float* __restrict__ p,
    unsigned* __restrict__ loc, const unsigned* __restrict__ chunkpref,
    float4* __restrict__ psort, int* __restrict__ svox, int N)
{
    const int i = blockIdx.x * TPB + threadIdx.x;
    if (i < N) {
        const int v = vidx[i];
        const unsigned pos = chunkpref[v >> 11] + atomicAdd(&loc[v], 1u);
        float4 r;
        r.x = p[3 * i + 0];
        r.y = p[3 * i + 1];
        r.z = p[3 * i + 2];
        r.w = __int_as_float(i);
        psort[pos] = r;
        svox[pos]  = v;
    }
}

// ---- L6: sorted fused gather + trilinear + MFMA projection ----
// Wave owns 16 sorted slots. Lane l: slot srow=l&15, octets kq=l>>4 and kq+4.
// Same-voxel samples adjacent -> coalescer merges identical corner-row reads.
// A-fragment = trilinear accumulator; 8x mfma_f32_16x16x32_bf16; C rows
// scattered to original sample ids via psort[slot].w.
__global__ __launch_bounds__(TPB) void gather_mfma_sorted(
    const unsigned* __restrict__ valbf,  // [K,32] u32 (bf16 x64, 128 B/row)
    const float4* __restrict__ psort,    // [N] {p.xyz, bitcast(n)}
    const int*   __restrict__ svox,      // [N]
    const uint4* __restrict__ wfrag,     // [8][64]
    const float* __restrict__ b,         // [64]
    const int*   __restrict__ feats,     // [V,8]
    float* __restrict__ out,             // [N,64]
    int N)
{
    const int t    = threadIdx.x;
    const int l    = t & 63;
    const int w    = t >> 6;
    const int base = blockIdx.x * 64 + 16 * w;
    const int srow = l & 15;
    const int kq   = l >> 4;

    const int slot = base + srow;
    const int cs   = (slot < N) ? slot : N - 1;

    const float4 rec = psort[cs];
    const int v = svox[cs];

    const int4 f0 = *(const int4*)&feats[(size_t)v * 8];
    const int4 f1 = *(const int4*)&feats[(size_t)v * 8 + 4];

    const float px = rec.x, py = rec.y, pz = rec.z;
    const float ox = 1.0f - px, oy = 1.0f - py, oz = 1.0f - pz;
    // corner order: [1,1,1],[1,1,0],[1,0,1],[0,1,1],[1,0,0],[0,1,0],[0,0,1],[0,0,0]
    float wgt[8];
    wgt[0] = px * py * pz;
    wgt[1] = px * py * oz;
    wgt[2] = px * oy * pz;
    wgt[3] = ox * py * pz;
    wgt[4] = px * oy * oz;
    wgt[5] = ox * py * oz;
    wgt[6] = ox * oy * pz;
    wgt[7] = ox * oy * oz;
    const int cidx[8] = {f0.x, f0.y, f0.z, f0.w, f1.x, f1.y, f1.z, f1.w};

    // all 16 gathers in one vmcnt window
    uint4 q0s[8], q1s[8];
    #pragma unroll
    for (int c = 0; c < 8; ++c) {
        const unsigned* row = valbf + (size_t)cidx[c] * 32;
        q0s[c] = *(const uint4*)(row + 4 * kq);
        q1s[c] = *(const uint4*)(row + 16 + 4 * kq);
    }

    float a0[8] = {0.f,0.f,0.f,0.f,0.f,0.f,0.f,0.f};
    float a1[8] = {0.f,0.f,0.f,0.f,0.f,0.f,0.f,0.f};
    #pragma unroll
    for (int c = 0; c < 8; ++c) {
        const uint4 q0 = q0s[c];
        const uint4 q1 = q1s[c];
        const float wc = wgt[c];
        a0[0] = fmaf(wc, bf_lo(q0.x), a0[0]);
        a0[1] = fmaf(wc, bf_hi(q0.x), a0[1]);
        a0[2] = fmaf(wc, bf_lo(q0.y), a0[2]);
        a0[3] = fmaf(wc, bf_hi(q0.y), a0[3]);
        a0[4] = fmaf(wc, bf_lo(q0.z), a0[4]);
        a0[5] = fmaf(wc, bf_hi(q0.z), a0[5]);
        a0[6] = fmaf(wc, bf_lo(q0.w), a0[6]);
        a0[7] = fmaf(wc, bf_hi(q0.w), a0[7]);
        a1[0] = fmaf(wc, bf_lo(q1.x), a1[0]);
        a1[1] = fmaf(wc, bf_hi(q1.x), a1[1]);
        a1[2] = fmaf(wc, bf_lo(q1.y), a1[2]);
        a1[3] = fmaf(wc, bf_hi(q1.y), a1[3]);
        a1[4] = fmaf(wc, bf_lo(q1.z), a1[4]);
        a1[5] = fmaf(wc, bf_hi(q1.z), a1[5]);
        a1[6] = fmaf(wc, bf_lo(q1.w), a1[6]);
        a1[7] = fmaf(wc, bf_hi(q1.w), a1[7]);
    }

    bf16x8 afrag0, afrag1;
    {
        union { unsigned u[4]; bf16x8 v; } cv;
        cv.u[0] = pack_bf16_rne(a0[0], a0[1]);
        cv.u[1] = pack_bf16_rne(a0[2], a0[3]);
        cv.u[2] = pack_bf16_rne(a0[4], a0[5]);
        cv.u[3] = pack_bf16_rne(a0[6], a0[7]);
        afrag0 = cv.v;
        cv.u[0] = pack_bf16_rne(a1[0], a1[1]);
        cv.u[1] = pack_bf16_rne(a1[2], a1[3]);
        cv.u[2] = pack_bf16_rne(a1[4], a1[5]);
        cv.u[3] = pack_bf16_rne(a1[6], a1[7]);
        afrag1 = cv.v;
    }

    // destination sample ids for this lane's 4 C rows (L1-hot psort lines)
    int nrow[4];
    #pragma unroll
    for (int r = 0; r < 4; ++r) {
        const int s2 = base + 4 * kq + r;
        nrow[r] = (s2 < N) ? __float_as_int(psort[s2].w) : -1;
    }

    #pragma unroll
    for (int ct = 0; ct < 4; ++ct) {
        const float bias = b[ct * 16 + srow];
        f32x4 acc;
        acc[0] = bias; acc[1] = bias; acc[2] = bias; acc[3] = bias;
        union { uint4 u; bf16x8 v; } b0, b1;
        b0.u = wfrag[(ct * 2 + 0) * 64 + l];
        b1.u = wfrag[(ct * 2 + 1) * 64 + l];
        acc = __builtin_amdgcn_mfma_f32_16x16x32_bf16(afrag0, b0.v, acc, 0, 0, 0);
        acc = __builtin_amdgcn_mfma_f32_16x16x32_bf16(afrag1, b1.v, acc, 0, 0, 0);

        const int col = ct * 16 + srow;
        #pragma unroll
        for (int r = 0; r < 4; ++r) {
            if (nrow[r] >= 0)
                __builtin_nontemporal_store(acc[r], &out[(size_t)nrow[r] * 64 + col]);
        }
    }
}

// ---- fallback 1: round-7 unsorted fused kernel (ws too small for sort) ----
__global__ __launch_bounds__(TPB) void fused_embed_proj_mfma(
    const unsigned* __restrict__ valbf, const float* __restrict__ p,
    const uint4* __restrict__ wfrag, const float* __restrict__ b,
    const int* __restrict__ feats, const int* __restrict__ vidx,
    float* __restrict__ out, int N)
{
    const int t    = threadIdx.x;
    const int l    = t & 63;
    const int w    = t >> 6;
    const int base = blockIdx.x * 64 + 16 * w;
    const int srow = l & 15;
    const int kq   = l >> 4;

    int n = base + srow;
    if (n >= N) n = N - 1;

    const int v = vidx[n];
    const int4 f0 = *(const int4*)&feats[(size_t)v * 8];
    const int4 f1 = *(const int4*)&feats[(size_t)v * 8 + 4];

    const float px = p[n * 3 + 0];
    const float py = p[n * 3 + 1];
    const float pz = p[n * 3 + 2];
    const float ox = 1.0f - px, oy = 1.0f - py, oz = 1.0f - pz;
    float wgt[8];
    wgt[0] = px * py * pz;
    wgt[1] = px * py * oz;
    wgt[2] = px * oy * pz;
    wgt[3] = ox * py * pz;
    wgt[4] = px * oy * oz;
    wgt[5] = ox * py * oz;
    wgt[6] = ox * oy * pz;
    wgt[7] = ox * oy * oz;
    const int cidx[8] = {f0.x, f0.y, f0.z, f0.w, f1.x, f1.y, f1.z, f1.w};

    uint4 q0s[8], q1s[8];
    #pragma unroll
    for (int c = 0; c < 8; ++c) {
        const unsigned* row = valbf + (size_t)cidx[c] * 32;
        q0s[c] = *(const uint4*)(row + 4 * kq);
        q1s[c] = *(const uint4*)(row + 16 + 4 * kq);
    }

    float a0[8] = {0.f,0.f,0.f,0.f,0.f,0.f,0.f,0.f};
    float a1[8] = {0.f,0.f,0.f,0.f,0.f,0.f,0.f,0.f};
    #pragma unroll
    for (int c = 0; c < 8; ++c) {
        const uint4 q0 = q0s[c];
        const uint4 q1 = q1s[c];
        const float wc = wgt[c];
        a0[0] = fmaf(wc, bf_lo(q0.x), a0[0]);
        a0[1] = fmaf(wc, bf_hi(q0.x), a0[1]);
        a0[2] = fmaf(wc, bf_lo(q0.y), a0[2]);
        a0[3] = fmaf(wc, bf_hi(q0.y), a0[3]);
        a0[4] = fmaf(wc, bf_lo(q0.z), a0[4]);
        a0[5] = fmaf(wc, bf_hi(q0.z), a0[5]);
        a0[6] = fmaf(wc, bf_lo(q0.w), a0[6]);
        a0[7] = fmaf(wc, bf_hi(q0.w), a0[7]);
        a1[0] = fmaf(wc, bf_lo(q1.x), a1[0]);
        a1[1] = fmaf(wc, bf_hi(q1.x), a1[1]);
        a1[2] = fmaf(wc, bf_lo(q1.y), a1[2]);
        a1[3] = fmaf(wc, bf_hi(q1.y), a1[3]);
        a1[4] = fmaf(wc, bf_lo(q1.z), a1[4]);
        a1[5] = fmaf(wc, bf_hi(q1.z), a1[5]);
        a1[6] = fmaf(wc, bf_lo(q1.w), a1[6]);
        a1[7] = fmaf(wc, bf_hi(q1.w), a1[7]);
    }

    bf16x8 afrag0, afrag1;
    {
        union { unsigned u[4]; bf16x8 v; } cv;
        cv.u[0] = pack_bf16_rne(a0[0], a0[1]);
        cv.u[1] = pack_bf16_rne(a0[2], a0[3]);
        cv.u[2] = pack_bf16_rne(a0[4], a0[5]);
        cv.u[3] = pack_bf16_rne(a0[6], a0[7]);
        afrag0 = cv.v;
        cv.u[0] = pack_bf16_rne(a1[0], a1[1]);
        cv.u[1] = pack_bf16_rne(a1[2], a1[3]);
        cv.u[2] = pack_bf16_rne(a1[4], a1[5]);
        cv.u[3] = pack_bf16_rne(a1[6], a1[7]);
        afrag1 = cv.v;
    }

    #pragma unroll
    for (int ct = 0; ct < 4; ++ct) {
        const float bias = b[ct * 16 + srow];
        f32x4 acc;
        acc[0] = bias; acc[1] = bias; acc[2] = bias; acc[3] = bias;
        union { uint4 u; bf16x8 v; } b0, b1;
        b0.u = wfrag[(ct * 2 + 0) * 64 + l];
        b1.u = wfrag[(ct * 2 + 1) * 64 + l];
        acc = __builtin_amdgcn_mfma_f32_16x16x32_bf16(afrag0, b0.v, acc, 0, 0, 0);
        acc = __builtin_amdgcn_mfma_f32_16x16x32_bf16(afrag1, b1.v, acc, 0, 0, 0);

        const int col = ct * 16 + srow;
        #pragma unroll
        for (int r = 0; r < 4; ++r) {
            const int n2 = base + 4 * kq + r;
            if (n2 < N)
                __builtin_nontemporal_store(acc[r], &out[(size_t)n2 * 64 + col]);
        }
    }
}

// ---- fallback 2: fp32 (tiny ws) ----
__global__ __launch_bounds__(TPB) void fused_embed_proj_fp32(
    const float* __restrict__ values, const float* __restrict__ p,
    const float* __restrict__ W, const float* __restrict__ b,
    const int* __restrict__ feats, const int* __restrict__ vidx,
    float* __restrict__ out, int N)
{
    __shared__ float featS[64][68];
    __shared__ float Wlds[64][64];

    const int t    = threadIdx.x;
    const int base = blockIdx.x * 64;
    {
        const float4* Wv = (const float4*)W;
        float4*       Wl = (float4*)&Wlds[0][0];
        #pragma unroll
        for (int i = 0; i < 4; ++i) Wl[t + i * TPB] = Wv[t + i * TPB];
    }
    const int g  = t & 15;
    const int sb = t >> 4;

    int   cidx[4][8];
    float wgt[4][8];
    #pragma unroll
    for (int i = 0; i < 4; ++i) {
        const int s = sb + 16 * i;
        int n = base + s;
        if (n >= N) n = N - 1;
        const int v = vidx[n];
        const int4 f0 = *(const int4*)&feats[(size_t)v * 8];
        const int4 f1 = *(const int4*)&feats[(size_t)v * 8 + 4];
        cidx[i][0] = f0.x; cidx[i][1] = f0.y; cidx[i][2] = f0.z; cidx[i][3] = f0.w;
        cidx[i][4] = f1.x; cidx[i][5] = f1.y; cidx[i][6] = f1.z; cidx[i][7] = f1.w;
        const float px = p[n * 3], py = p[n * 3 + 1], pz = p[n * 3 + 2];
        const float ox = 1.f - px, oy = 1.f - py, oz = 1.f - pz;
        wgt[i][0] = px * py * pz; wgt[i][1] = px * py * oz;
        wgt[i][2] = px * oy * pz; wgt[i][3] = ox * py * pz;
        wgt[i][4] = px * oy * oz; wgt[i][5] = ox * py * oz;
        wgt[i][6] = ox * oy * pz; wgt[i][7] = ox * oy * oz;
    }
    #pragma unroll
    for (int i = 0; i < 4; ++i) {
        float4 acc; acc.x = acc.y = acc.z = acc.w = 0.f;
        #pragma unroll
        for (int c = 0; c < 8; ++c) {
            const float4 val = *(const float4*)&values[(size_t)cidx[i][c] * 64 + 4 * g];
            const float w = wgt[i][c];
            acc.x = fmaf(w, val.x, acc.x); acc.y = fmaf(w, val.y, acc.y);
            acc.z = fmaf(w, val.z, acc.z); acc.w = fmaf(w, val.w, acc.w);
        }
        *(float4*)&featS[sb + 16 * i][4 * g] = acc;
    }
    __syncthreads();

    const int tx = t & 15, ty = t >> 4;
    float acc[4][4];
    {
        const float4 bb = ((const float4*)b)[tx];
        #pragma unroll
        for (int j = 0; j < 4; ++j) {
            acc[j][0] = bb.x; acc[j][1] = bb.y; acc[j][2] = bb.z; acc[j][3] = bb.w;
        }
    }
    #pragma unroll 4
    for (int d = 0; d < 64; ++d) {
        const float a0 = featS[4 * ty + 0][d];
        const float a1 = featS[4 * ty + 1][d];
        const float a2 = featS[4 * ty + 2][d];
        const float a3 = featS[4 * ty + 3][d];
        const float4 wr = *(const float4*)&Wlds[d][4 * tx];
        acc[0][0] = fmaf(a0, wr.x, acc[0][0]); acc[0][1] = fmaf(a0, wr.y, acc[0][1]);
        acc[0][2] = fmaf(a0, wr.z, acc[0][2]); acc[0][3] = fmaf(a0, wr.w, acc[0][3]);
        acc[1][0] = fmaf(a1, wr.x, acc[1][0]); acc[1][1] = fmaf(a1, wr.y, acc[1][1]);
        acc[1][2] = fmaf(a1, wr.z, acc[1][2]); acc[1][3] = fmaf(a1, wr.w, acc[1][3]);
        acc[2][0] = fmaf(a2, wr.x, acc[2][0]); acc[2][1] = fmaf(a2, wr.y, acc[2][1]);
        acc[2][2] = fmaf(a2, wr.z, acc[2][2]); acc[2][3] = fmaf(a2, wr.w, acc[2][3]);
        acc[3][0] = fmaf(a3, wr.x, acc[3][0]); acc[3][1] = fmaf(a3, wr.y, acc[3][1]);
        acc[3][2] = fmaf(a3, wr.z, acc[3][2]); acc[3][3] = fmaf(a3, wr.w, acc[3][3]);
    }
    #pragma unroll
    for (int j = 0; j < 4; ++j) {
        const int n = base + 4 * ty + j;
        if (n < N) {
            float4 o; o.x = acc[j][0]; o.y = acc[j][1]; o.z = acc[j][2]; o.w = acc[j][3];
            *(float4*)&out[(size_t)n * 64 + 4 * tx] = o;
        }
    }
}

extern "C" void kernel_launch(void* const* d_in, const int* in_sizes, int n_in,
                              void* d_out, int out_size, void* d_ws, size_t ws_size,
                              hipStream_t stream) {
    const float* values = (const float*)d_in[0];
    const float* p      = (const float*)d_in[1];
    const float* W      = (const float*)d_in[2];
    const float* b      = (const float*)d_in[3];
    const int*   feats  = (const int*)d_in[4];
    const int*   vidx   = (const int*)d_in[5];
    float* out = (float*)d_out;

    const int N  = in_sizes[5];
    const int KD = in_sizes[0];            // K * 64
    const int V  = in_sizes[4] / 8;
    const int nblocks = (N + 63) / 64;
    const int n8  = KD / 8;
    const int nvb = (n8 + TPB - 1) / TPB;
    const int zb  = (V + TPB - 1) / TPB;
    const int nchunks = (V + 2047) / 2048;

    // ws layout: valbf | wfrag | cnt | loc | csum | cpref | psort | svox
    auto align256 = [](size_t x) { return (x + 255) & ~(size_t)255; };
    const size_t valbf_off = 0;
    const size_t wfrag_off = align256((size_t)KD * 2);
    const size_t cnt_off   = wfrag_off + align256((size_t)8192);
    const size_t loc_off   = cnt_off + align256((size_t)V * 4);
    const size_t csum_off  = loc_off + align256((size_t)V * 4);
    const size_t cpref_off = csum_off + align256((size_t)nchunks * 4);
    const size_t psort_off = cpref_off + align256((size_t)nchunks * 4);
    const size_t svox_off  = psort_off + align256((size_t)N * 16);
    const size_t need_sort = svox_off + align256((size_t)N * 4);
    const size_t need_mfma = wfrag_off + 8192;

    if (ws_size >= need_sort && nchunks <= TPB) {
        unsigned* valbf  = (unsigned*)((char*)d_ws + valbf_off);
        uint4*    wfrag  = (uint4*)((char*)d_ws + wfrag_off);
        unsigned* cnt    = (unsigned*)((char*)d_ws + cnt_off);
        unsigned* loc    = (unsigned*)((char*)d_ws + loc_off);
        unsigned* csum   = (unsigned*)((char*)d_ws + csum_off);
        unsigned* cpref  = (unsigned*)((char*)d_ws + cpref_off);
        float4*   psort  = (float4*)((char*)d_ws + psort_off);
        int*      svox   = (int*)((char*)d_ws + svox_off);

        prep_combo<<<nvb + zb + 1, TPB, 0, stream>>>(
            (const float4*)values, (uint4*)valbf, n8, nvb, cnt, V, zb, W, wfrag);
        hist_kernel<<<(N + TPB - 1) / TPB, TPB, 0, stream>>>(vidx, cnt, N);
        scan1_kernel<<<nchunks, TPB, 0, stream>>>(cnt, loc, csum, V);
        scan2_kernel<<<1, TPB, 0, stream>>>(csum, cpref, nchunks);
        scatter_kernel<<<(N + TPB - 1) / TPB, TPB, 0, stream>>>(
            vidx, p, loc, cpref, psort, svox, N);
        gather_mfma_sorted<<<nblocks, TPB, 0, stream>>>(
            valbf, psort, svox, wfrag, b, feats, out, N);
    } else if (ws_size >= need_mfma) {
        unsigned* valbf = (unsigned*)((char*)d_ws + valbf_off);
        uint4*    wfrag = (uint4*)((char*)d_ws + wfrag_off);
        prep_combo<<<nvb + 1, TPB, 0, stream>>>(
            (const float4*)values, (uint4*)valbf, n8, nvb, nullptr, 0, 0, W, wfrag);
        fused_embed_proj_mfma<<<nblocks, TPB, 0, stream>>>(
            valbf, p, wfrag, b, feats, vidx, out, N);
    } else {
        fused_embed_proj_fp32<<<nblocks, TPB, 0, stream>>>(
            values, p, W, b, feats, vidx, out, N);
    }
}

// Round 13
// 69.015 us; speedup vs baseline: 3.5585x; 1.1832x over previous
//
#include <hip/hip_runtime.h>

#define TPB 256

typedef __attribute__((ext_vector_type(8))) short bf16x8;
typedef __attribute__((ext_vector_type(4))) float f32x4;

__device__ __forceinline__ unsigned pack_bf16_rne(float lo, float hi) {
    union { float f; unsigned u; } a, b;
    a.f = lo; b.f = hi;
    unsigned ua = (a.u + 0x7fffu + ((a.u >> 16) & 1u)) >> 16;
    unsigned ub = (b.u + 0x7fffu + ((b.u >> 16) & 1u)) >> 16;
    return ua | (ub << 16);
}
__device__ __forceinline__ float bf_lo(unsigned u) {
    union { unsigned i; float f; } c; c.i = u << 16; return c.f;
}
__device__ __forceinline__ float bf_hi(unsigned u) {
    union { unsigned i; float f; } c; c.i = u & 0xffff0000u; return c.f;
}

// ---- merged conversion: values fp32 -> bf16 table, plus W -> MFMA B-frags ----
__global__ __launch_bounds__(TPB) void cvt_inputs(
    const float4* __restrict__ src, uint4* __restrict__ dst, int n8,
    const float* __restrict__ W, uint4* __restrict__ wfrag, int nvb)
{
    if ((int)blockIdx.x == nvb) {
        const int t = threadIdx.x;
        for (int e = t; e < 512; e += TPB) {
            const int l  = e & 63;
            const int f  = e >> 6;
            const int ct = f >> 1;
            const int kf = f & 1;
            const int col = ct * 16 + (l & 15);
            const int k0  = kf * 32 + 8 * (l >> 4);
            uint4 o;
            o.x = pack_bf16_rne(W[(k0 + 0) * 64 + col], W[(k0 + 1) * 64 + col]);
            o.y = pack_bf16_rne(W[(k0 + 2) * 64 + col], W[(k0 + 3) * 64 + col]);
            o.z = pack_bf16_rne(W[(k0 + 4) * 64 + col], W[(k0 + 5) * 64 + col]);
            o.w = pack_bf16_rne(W[(k0 + 6) * 64 + col], W[(k0 + 7) * 64 + col]);
            wfrag[e] = o;
        }
        return;
    }
    const int i = blockIdx.x * TPB + threadIdx.x;
    if (i < n8) {
        const float4 a = src[2 * i];
        const float4 b = src[2 * i + 1];
        uint4 o;
        o.x = pack_bf16_rne(a.x, a.y);
        o.y = pack_bf16_rne(a.z, a.w);
        o.z = pack_bf16_rne(b.x, b.y);
        o.w = pack_bf16_rne(b.z, b.w);
        dst[i] = o;
    }
}

// ---- main fused kernel: gather-direct-to-A-fragment, zero LDS, no barrier ----
// (round-7 structure) + sched_barrier(0) to FORCE all 16 gathers issued before
// any accumulation (one vmcnt window, max memory-level parallelism), and
// __launch_bounds__(TPB,1) so the allocator may keep 16 x uint4 live.
__global__ __launch_bounds__(TPB, 1) void fused_embed_proj_mfma(
    const unsigned* __restrict__ valbf,  // [K,32] packed bf16 rows (128 B/row)
    const float* __restrict__ p,         // [N,3]
    const uint4* __restrict__ wfrag,     // [8][64] B-fragments
    const float* __restrict__ b,         // [64]
    const int*   __restrict__ feats,     // [V,8]
    const int*   __restrict__ vidx,      // [N]
    float* __restrict__ out,             // [N,64]
    int N)
{
    const int t    = threadIdx.x;
    const int l    = t & 63;
    const int w    = t >> 6;
    const int base = blockIdx.x * 64 + 16 * w;   // this wave's 16-sample tile
    const int srow = l & 15;
    const int kq   = l >> 4;                     // k-octet 0..3

    int n = base + srow;
    if (n >= N) n = N - 1;                       // clamped lanes' rows never stored

    // ---- corner indices + trilinear weights ----
    const int v = vidx[n];
    const int4 f0 = *(const int4*)&feats[(size_t)v * 8];
    const int4 f1 = *(const int4*)&feats[(size_t)v * 8 + 4];

    const float px = p[n * 3 + 0];
    const float py = p[n * 3 + 1];
    const float pz = p[n * 3 + 2];
    const float ox = 1.0f - px, oy = 1.0f - py, oz = 1.0f - pz;
    // corner order: [1,1,1],[1,1,0],[1,0,1],[0,1,1],[1,0,0],[0,1,0],[0,0,1],[0,0,0]
    float wgt[8];
    wgt[0] = px * py * pz;
    wgt[1] = px * py * oz;
    wgt[2] = px * oy * pz;
    wgt[3] = ox * py * pz;
    wgt[4] = px * oy * oz;
    wgt[5] = ox * py * oz;
    wgt[6] = ox * oy * pz;
    wgt[7] = ox * oy * oz;
    const int cidx[8] = {f0.x, f0.y, f0.z, f0.w, f1.x, f1.y, f1.z, f1.w};

    // ---- issue ALL 16 gathers; sched_barrier(0) pins them BEFORE any use ----
    uint4 q0s[8], q1s[8];
    #pragma unroll
    for (int c = 0; c < 8; ++c) {
        const unsigned* row = valbf + (size_t)cidx[c] * 32;
        q0s[c] = *(const uint4*)(row + 4 * kq);        // octet kq      (dims 8kq..)
        q1s[c] = *(const uint4*)(row + 16 + 4 * kq);   // octet kq+4    (dims 32+8kq..)
    }
    __builtin_amdgcn_sched_barrier(0);   // no reordering across: 16 loads in flight

    // ---- weighted accumulate -> fp32 A-fragment accumulators ----
    float a0[8] = {0.f,0.f,0.f,0.f,0.f,0.f,0.f,0.f};
    float a1[8] = {0.f,0.f,0.f,0.f,0.f,0.f,0.f,0.f};
    #pragma unroll
    for (int c = 0; c < 8; ++c) {
        const uint4 q0 = q0s[c];
        const uint4 q1 = q1s[c];
        const float wc = wgt[c];
        a0[0] = fmaf(wc, bf_lo(q0.x), a0[0]);
        a0[1] = fmaf(wc, bf_hi(q0.x), a0[1]);
        a0[2] = fmaf(wc, bf_lo(q0.y), a0[2]);
        a0[3] = fmaf(wc, bf_hi(q0.y), a0[3]);
        a0[4] = fmaf(wc, bf_lo(q0.z), a0[4]);
        a0[5] = fmaf(wc, bf_hi(q0.z), a0[5]);
        a0[6] = fmaf(wc, bf_lo(q0.w), a0[6]);
        a0[7] = fmaf(wc, bf_hi(q0.w), a0[7]);
        a1[0] = fmaf(wc, bf_lo(q1.x), a1[0]);
        a1[1] = fmaf(wc, bf_hi(q1.x), a1[1]);
        a1[2] = fmaf(wc, bf_lo(q1.y), a1[2]);
        a1[3] = fmaf(wc, bf_hi(q1.y), a1[3]);
        a1[4] = fmaf(wc, bf_lo(q1.z), a1[4]);
        a1[5] = fmaf(wc, bf_hi(q1.z), a1[5]);
        a1[6] = fmaf(wc, bf_lo(q1.w), a1[6]);
        a1[7] = fmaf(wc, bf_hi(q1.w), a1[7]);
    }

    // ---- pack accumulators into MFMA A-fragments ----
    bf16x8 afrag0, afrag1;
    {
        union { unsigned u[4]; bf16x8 v; } cv;
        cv.u[0] = pack_bf16_rne(a0[0], a0[1]);
        cv.u[1] = pack_bf16_rne(a0[2], a0[3]);
        cv.u[2] = pack_bf16_rne(a0[4], a0[5]);
        cv.u[3] = pack_bf16_rne(a0[6], a0[7]);
        afrag0 = cv.v;
        cv.u[0] = pack_bf16_rne(a1[0], a1[1]);
        cv.u[1] = pack_bf16_rne(a1[2], a1[3]);
        cv.u[2] = pack_bf16_rne(a1[4], a1[5]);
        cv.u[3] = pack_bf16_rne(a1[6], a1[7]);
        afrag1 = cv.v;
    }

    // ---- projection: 4 col-tiles x 2 MFMAs, W frags from L1 ----
    #pragma unroll
    for (int ct = 0; ct < 4; ++ct) {
        const float bias = b[ct * 16 + srow];
        f32x4 acc;
        acc[0] = bias; acc[1] = bias; acc[2] = bias; acc[3] = bias;
        union { uint4 u; bf16x8 v; } b0, b1;
        b0.u = wfrag[(ct * 2 + 0) * 64 + l];
        b1.u = wfrag[(ct * 2 + 1) * 64 + l];
        acc = __builtin_amdgcn_mfma_f32_16x16x32_bf16(afrag0, b0.v, acc, 0, 0, 0);
        acc = __builtin_amdgcn_mfma_f32_16x16x32_bf16(afrag1, b1.v, acc, 0, 0, 0);

        const int col = ct * 16 + srow;          // C col = lane&15
        #pragma unroll
        for (int r = 0; r < 4; ++r) {
            const int n2 = base + 4 * kq + r;    // C row = (lane>>4)*4 + r
            if (n2 < N)
                __builtin_nontemporal_store(acc[r], &out[(size_t)n2 * 64 + col]);
        }
    }
}

// ---- fallback: proven round-2 fp32 kernel (used only if ws too small) ----
__global__ __launch_bounds__(TPB) void fused_embed_proj_fp32(
    const float* __restrict__ values, const float* __restrict__ p,
    const float* __restrict__ W, const float* __restrict__ b,
    const int* __restrict__ feats, const int* __restrict__ vidx,
    float* __restrict__ out, int N)
{
    __shared__ float featS[64][68];
    __shared__ float Wlds[64][64];

    const int t    = threadIdx.x;
    const int base = blockIdx.x * 64;
    {
        const float4* Wv = (const float4*)W;
        float4*       Wl = (float4*)&Wlds[0][0];
        #pragma unroll
        for (int i = 0; i < 4; ++i) Wl[t + i * TPB] = Wv[t + i * TPB];
    }
    const int g  = t & 15;
    const int sb = t >> 4;

    int   cidx[4][8];
    float wgt[4][8];
    #pragma unroll
    for (int i = 0; i < 4; ++i) {
        const int s = sb + 16 * i;
        int n = base + s;
        if (n >= N) n = N - 1;
        const int v = vidx[n];
        const int4 f0 = *(const int4*)&feats[(size_t)v * 8];
        const int4 f1 = *(const int4*)&feats[(size_t)v * 8 + 4];
        cidx[i][0] = f0.x; cidx[i][1] = f0.y; cidx[i][2] = f0.z; cidx[i][3] = f0.w;
        cidx[i][4] = f1.x; cidx[i][5] = f1.y; cidx[i][6] = f1.z; cidx[i][7] = f1.w;
        const float px = p[n * 3], py = p[n * 3 + 1], pz = p[n * 3 + 2];
        const float ox = 1.f - px, oy = 1.f - py, oz = 1.f - pz;
        wgt[i][0] = px * py * pz; wgt[i][1] = px * py * oz;
        wgt[i][2] = px * oy * pz; wgt[i][3] = ox * py * pz;
        wgt[i][4] = px * oy * oz; wgt[i][5] = ox * py * oz;
        wgt[i][6] = ox * oy * pz; wgt[i][7] = ox * oy * oz;
    }
    #pragma unroll
    for (int i = 0; i < 4; ++i) {
        float4 acc; acc.x = acc.y = acc.z = acc.w = 0.f;
        #pragma unroll
        for (int c = 0; c < 8; ++c) {
            const float4 val = *(const float4*)&values[(size_t)cidx[i][c] * 64 + 4 * g];
            const float w = wgt[i][c];
            acc.x = fmaf(w, val.x, acc.x); acc.y = fmaf(w, val.y, acc.y);
            acc.z = fmaf(w, val.z, acc.z); acc.w = fmaf(w, val.w, acc.w);
        }
        *(float4*)&featS[sb + 16 * i][4 * g] = acc;
    }
    __syncthreads();

    const int tx = t & 15, ty = t >> 4;
    float acc[4][4];
    {
        const float4 bb = ((const float4*)b)[tx];
        #pragma unroll
        for (int j = 0; j < 4; ++j) {
            acc[j][0] = bb.x; acc[j][1] = bb.y; acc[j][2] = bb.z; acc[j][3] = bb.w;
        }
    }
    #pragma unroll 4
    for (int d = 0; d < 64; ++d) {
        const float a0 = featS[4 * ty + 0][d];
        const float a1 = featS[4 * ty + 1][d];
        const float a2 = featS[4 * ty + 2][d];
        const float a3 = featS[4 * ty + 3][d];
        const float4 wr = *(const float4*)&Wlds[d][4 * tx];
        acc[0][0] = fmaf(a0, wr.x, acc[0][0]); acc[0][1] = fmaf(a0, wr.y, acc[0][1]);
        acc[0][2] = fmaf(a0, wr.z, acc[0][2]); acc[0][3] = fmaf(a0, wr.w, acc[0][3]);
        acc[1][0] = fmaf(a1, wr.x, acc[1][0]); acc[1][1] = fmaf(a1, wr.y, acc[1][1]);
        acc[1][2] = fmaf(a1, wr.z, acc[1][2]); acc[1][3] = fmaf(a1, wr.w, acc[1][3]);
        acc[2][0] = fmaf(a2, wr.x, acc[2][0]); acc[2][1] = fmaf(a2, wr.y, acc[2][1]);
        acc[2][2] = fmaf(a2, wr.z, acc[2][2]); acc[2][3] = fmaf(a2, wr.w, acc[2][3]);
        acc[3][0] = fmaf(a3, wr.x, acc[3][0]); acc[3][1] = fmaf(a3, wr.y, acc[3][1]);
        acc[3][2] = fmaf(a3, wr.z, acc[3][2]); acc[3][3] = fmaf(a3, wr.w, acc[3][3]);
    }
    #pragma unroll
    for (int j = 0; j < 4; ++j) {
        const int n = base + 4 * ty + j;
        if (n < N) {
            float4 o; o.x = acc[j][0]; o.y = acc[j][1]; o.z = acc[j][2]; o.w = acc[j][3];
            *(float4*)&out[(size_t)n * 64 + 4 * tx] = o;
        }
    }
}

extern "C" void kernel_launch(void* const* d_in, const int* in_sizes, int n_in,
                              void* d_out, int out_size, void* d_ws, size_t ws_size,
                              hipStream_t stream) {
    const float* values = (const float*)d_in[0];
    const float* p      = (const float*)d_in[1];
    const float* W      = (const float*)d_in[2];
    const float* b      = (const float*)d_in[3];
    const int*   feats  = (const int*)d_in[4];
    const int*   vidx   = (const int*)d_in[5];
    float* out = (float*)d_out;

    const int N  = in_sizes[5];
    const int KD = in_sizes[0];            // K * 64
    const int nblocks = (N + 63) / 64;

    const size_t val_bytes = (size_t)KD * 2;
    const size_t need      = val_bytes + 8192;
    if (ws_size >= need) {
        unsigned* valbf = (unsigned*)d_ws;
        uint4*    wfrag = (uint4*)((char*)d_ws + val_bytes);
        const int n8  = KD / 8;
        const int nvb = (n8 + TPB - 1) / TPB;
        cvt_inputs<<<nvb + 1, TPB, 0, stream>>>(
            (const float4*)values, (uint4*)valbf, n8, W, wfrag, nvb);
        fused_embed_proj_mfma<<<nblocks, TPB, 0, stream>>>(
            valbf, p, wfrag, b, feats, vidx, out, N);
    } else {
        fused_embed_proj_fp32<<<nblocks, TPB, 0, stream>>>(
            values, p, W, b, feats, vidx, out, N);
    }
}

// Round 14
// 65.230 us; speedup vs baseline: 3.7649x; 1.0580x over previous
//
#include <hip/hip_runtime.h>

#define TPB 256

typedef __attribute__((ext_vector_type(8))) short bf16x8;
typedef __attribute__((ext_vector_type(4))) float f32x4;
typedef __attribute__((ext_vector_type(4))) unsigned u32x4;

__device__ __forceinline__ unsigned pack_bf16_rne(float lo, float hi) {
    union { float f; unsigned u; } a, b;
    a.f = lo; b.f = hi;
    unsigned ua = (a.u + 0x7fffu + ((a.u >> 16) & 1u)) >> 16;
    unsigned ub = (b.u + 0x7fffu + ((b.u >> 16) & 1u)) >> 16;
    return ua | (ub << 16);
}
__device__ __forceinline__ float bf_lo(unsigned u) {
    union { unsigned i; float f; } c; c.i = u << 16; return c.f;
}
__device__ __forceinline__ float bf_hi(unsigned u) {
    union { unsigned i; float f; } c; c.i = u & 0xffff0000u; return c.f;
}

// ---- merged conversion: values fp32 -> bf16 table, plus W -> MFMA B-frags ----
__global__ __launch_bounds__(TPB) void cvt_inputs(
    const float4* __restrict__ src, uint4* __restrict__ dst, int n8,
    const float* __restrict__ W, uint4* __restrict__ wfrag, int nvb)
{
    if ((int)blockIdx.x == nvb) {
        const int t = threadIdx.x;
        for (int e = t; e < 512; e += TPB) {
            const int l  = e & 63;
            const int f  = e >> 6;
            const int ct = f >> 1;
            const int kf = f & 1;
            const int col = ct * 16 + (l & 15);
            const int k0  = kf * 32 + 8 * (l >> 4);
            uint4 o;
            o.x = pack_bf16_rne(W[(k0 + 0) * 64 + col], W[(k0 + 1) * 64 + col]);
            o.y = pack_bf16_rne(W[(k0 + 2) * 64 + col], W[(k0 + 3) * 64 + col]);
            o.z = pack_bf16_rne(W[(k0 + 4) * 64 + col], W[(k0 + 5) * 64 + col]);
            o.w = pack_bf16_rne(W[(k0 + 6) * 64 + col], W[(k0 + 7) * 64 + col]);
            wfrag[e] = o;
        }
        return;
    }
    const int i = blockIdx.x * TPB + threadIdx.x;
    if (i < n8) {
        const float4 a = src[2 * i];
        const float4 b = src[2 * i + 1];
        uint4 o;
        o.x = pack_bf16_rne(a.x, a.y);
        o.y = pack_bf16_rne(a.z, a.w);
        o.z = pack_bf16_rne(b.x, b.y);
        o.w = pack_bf16_rne(b.z, b.w);
        dst[i] = o;
    }
}

// ---- main fused kernel: gather-direct-to-A-fragment, zero LDS, no barrier ----
// Inline-asm global_load_dwordx4 for the 16 gathers: 16 "=v" u32x4 outputs force
// all dest registers live -> all 16 loads genuinely outstanding in ONE vmcnt
// window (the compiler refused to do this from C; VGPR=68 in rounds 7-13 was
// the proof). Explicit s_waitcnt vmcnt(0) + sched_barrier(0) before use.
__global__ __launch_bounds__(TPB, 1) void fused_embed_proj_mfma(
    const unsigned* __restrict__ valbf,  // [K,32] packed bf16 rows (128 B/row)
    const float* __restrict__ p,         // [N,3]
    const uint4* __restrict__ wfrag,     // [8][64] B-fragments
    const float* __restrict__ b,         // [64]
    const int*   __restrict__ feats,     // [V,8]
    const int*   __restrict__ vidx,      // [N]
    float* __restrict__ out,             // [N,64]
    int N)
{
    const int t    = threadIdx.x;
    const int l    = t & 63;
    const int w    = t >> 6;
    const int base = blockIdx.x * 64 + 16 * w;   // this wave's 16-sample tile
    const int srow = l & 15;
    const int kq   = l >> 4;                     // k-octet 0..3

    int n = base + srow;
    if (n >= N) n = N - 1;                       // clamped lanes' rows never stored

    // ---- corner indices + trilinear weights ----
    const int v = vidx[n];
    const int4 f0 = *(const int4*)&feats[(size_t)v * 8];
    const int4 f1 = *(const int4*)&feats[(size_t)v * 8 + 4];

    const float px = p[n * 3 + 0];
    const float py = p[n * 3 + 1];
    const float pz = p[n * 3 + 2];
    const float ox = 1.0f - px, oy = 1.0f - py, oz = 1.0f - pz;
    // corner order: [1,1,1],[1,1,0],[1,0,1],[0,1,1],[1,0,0],[0,1,0],[0,0,1],[0,0,0]
    float wgt[8];
    wgt[0] = px * py * pz;
    wgt[1] = px * py * oz;
    wgt[2] = px * oy * pz;
    wgt[3] = ox * py * pz;
    wgt[4] = px * oy * oz;
    wgt[5] = ox * py * oz;
    wgt[6] = ox * oy * pz;
    wgt[7] = ox * oy * oz;
    const int cidx[8] = {f0.x, f0.y, f0.z, f0.w, f1.x, f1.y, f1.z, f1.w};

    // ---- 16 forced-parallel gathers: inline asm, one vmcnt window ----
    const unsigned* rows[8];
    #pragma unroll
    for (int c = 0; c < 8; ++c)
        rows[c] = valbf + (size_t)cidx[c] * 32 + 4 * kq;

    u32x4 q0s[8], q1s[8];
    #pragma unroll
    for (int c = 0; c < 8; ++c) {
        asm volatile("global_load_dwordx4 %0, %1, off"
                     : "=v"(q0s[c]) : "v"(rows[c]));
        asm volatile("global_load_dwordx4 %0, %1, off offset:64"
                     : "=v"(q1s[c]) : "v"(rows[c]));
    }
    asm volatile("s_waitcnt vmcnt(0)" ::: "memory");
    __builtin_amdgcn_sched_barrier(0);   // rule 18: keep consumers below the wait

    // ---- weighted accumulate -> fp32 A-fragment accumulators ----
    float a0[8] = {0.f,0.f,0.f,0.f,0.f,0.f,0.f,0.f};
    float a1[8] = {0.f,0.f,0.f,0.f,0.f,0.f,0.f,0.f};
    #pragma unroll
    for (int c = 0; c < 8; ++c) {
        const u32x4 q0 = q0s[c];
        const u32x4 q1 = q1s[c];
        const float wc = wgt[c];
        a0[0] = fmaf(wc, bf_lo(q0[0]), a0[0]);
        a0[1] = fmaf(wc, bf_hi(q0[0]), a0[1]);
        a0[2] = fmaf(wc, bf_lo(q0[1]), a0[2]);
        a0[3] = fmaf(wc, bf_hi(q0[1]), a0[3]);
        a0[4] = fmaf(wc, bf_lo(q0[2]), a0[4]);
        a0[5] = fmaf(wc, bf_hi(q0[2]), a0[5]);
        a0[6] = fmaf(wc, bf_lo(q0[3]), a0[6]);
        a0[7] = fmaf(wc, bf_hi(q0[3]), a0[7]);
        a1[0] = fmaf(wc, bf_lo(q1[0]), a1[0]);
        a1[1] = fmaf(wc, bf_hi(q1[0]), a1[1]);
        a1[2] = fmaf(wc, bf_lo(q1[1]), a1[2]);
        a1[3] = fmaf(wc, bf_hi(q1[1]), a1[3]);
        a1[4] = fmaf(wc, bf_lo(q1[2]), a1[4]);
        a1[5] = fmaf(wc, bf_hi(q1[2]), a1[5]);
        a1[6] = fmaf(wc, bf_lo(q1[3]), a1[6]);
        a1[7] = fmaf(wc, bf_hi(q1[3]), a1[7]);
    }

    // ---- pack accumulators into MFMA A-fragments ----
    bf16x8 afrag0, afrag1;
    {
        union { unsigned u[4]; bf16x8 v; } cv;
        cv.u[0] = pack_bf16_rne(a0[0], a0[1]);
        cv.u[1] = pack_bf16_rne(a0[2], a0[3]);
        cv.u[2] = pack_bf16_rne(a0[4], a0[5]);
        cv.u[3] = pack_bf16_rne(a0[6], a0[7]);
        afrag0 = cv.v;
        cv.u[0] = pack_bf16_rne(a1[0], a1[1]);
        cv.u[1] = pack_bf16_rne(a1[2], a1[3]);
        cv.u[2] = pack_bf16_rne(a1[4], a1[5]);
        cv.u[3] = pack_bf16_rne(a1[6], a1[7]);
        afrag1 = cv.v;
    }

    // ---- projection: 4 col-tiles x 2 MFMAs, W frags from L1 ----
    #pragma unroll
    for (int ct = 0; ct < 4; ++ct) {
        const float bias = b[ct * 16 + srow];
        f32x4 acc;
        acc[0] = bias; acc[1] = bias; acc[2] = bias; acc[3] = bias;
        union { uint4 u; bf16x8 v; } b0, b1;
        b0.u = wfrag[(ct * 2 + 0) * 64 + l];
        b1.u = wfrag[(ct * 2 + 1) * 64 + l];
        acc = __builtin_amdgcn_mfma_f32_16x16x32_bf16(afrag0, b0.v, acc, 0, 0, 0);
        acc = __builtin_amdgcn_mfma_f32_16x16x32_bf16(afrag1, b1.v, acc, 0, 0, 0);

        const int col = ct * 16 + srow;          // C col = lane&15
        #pragma unroll
        for (int r = 0; r < 4; ++r) {
            const int n2 = base + 4 * kq + r;    // C row = (lane>>4)*4 + r
            if (n2 < N)
                __builtin_nontemporal_store(acc[r], &out[(size_t)n2 * 64 + col]);
        }
    }
}

// ---- fallback: proven round-2 fp32 kernel (used only if ws too small) ----
__global__ __launch_bounds__(TPB) void fused_embed_proj_fp32(
    const float* __restrict__ values, const float* __restrict__ p,
    const float* __restrict__ W, const float* __restrict__ b,
    const int* __restrict__ feats, const int* __restrict__ vidx,
    float* __restrict__ out, int N)
{
    __shared__ float featS[64][68];
    __shared__ float Wlds[64][64];

    const int t    = threadIdx.x;
    const int base = blockIdx.x * 64;
    {
        const float4* Wv = (const float4*)W;
        float4*       Wl = (float4*)&Wlds[0][0];
        #pragma unroll
        for (int i = 0; i < 4; ++i) Wl[t + i * TPB] = Wv[t + i * TPB];
    }
    const int g  = t & 15;
    const int sb = t >> 4;

    int   cidx[4][8];
    float wgt[4][8];
    #pragma unroll
    for (int i = 0; i < 4; ++i) {
        const int s = sb + 16 * i;
        int n = base + s;
        if (n >= N) n = N - 1;
        const int v = vidx[n];
        const int4 f0 = *(const int4*)&feats[(size_t)v * 8];
        const int4 f1 = *(const int4*)&feats[(size_t)v * 8 + 4];
        cidx[i][0] = f0.x; cidx[i][1] = f0.y; cidx[i][2] = f0.z; cidx[i][3] = f0.w;
        cidx[i][4] = f1.x; cidx[i][5] = f1.y; cidx[i][6] = f1.z; cidx[i][7] = f1.w;
        const float px = p[n * 3], py = p[n * 3 + 1], pz = p[n * 3 + 2];
        const float ox = 1.f - px, oy = 1.f - py, oz = 1.f - pz;
        wgt[i][0] = px * py * pz; wgt[i][1] = px * py * oz;
        wgt[i][2] = px * oy * pz; wgt[i][3] = ox * py * pz;
        wgt[i][4] = px * oy * oz; wgt[i][5] = ox * py * oz;
        wgt[i][6] = ox * oy * pz; wgt[i][7] = ox * oy * oz;
    }
    #pragma unroll
    for (int i = 0; i < 4; ++i) {
        float4 acc; acc.x = acc.y = acc.z = acc.w = 0.f;
        #pragma unroll
        for (int c = 0; c < 8; ++c) {
            const float4 val = *(const float4*)&values[(size_t)cidx[i][c] * 64 + 4 * g];
            const float w = wgt[i][c];
            acc.x = fmaf(w, val.x, acc.x); acc.y = fmaf(w, val.y, acc.y);
            acc.z = fmaf(w, val.z, acc.z); acc.w = fmaf(w, val.w, acc.w);
        }
        *(float4*)&featS[sb + 16 * i][4 * g] = acc;
    }
    __syncthreads();

    const int tx = t & 15, ty = t >> 4;
    float acc[4][4];
    {
        const float4 bb = ((const float4*)b)[tx];
        #pragma unroll
        for (int j = 0; j < 4; ++j) {
            acc[j][0] = bb.x; acc[j][1] = bb.y; acc[j][2] = bb.z; acc[j][3] = bb.w;
        }
    }
    #pragma unroll 4
    for (int d = 0; d < 64; ++d) {
        const float a0 = featS[4 * ty + 0][d];
        const float a1 = featS[4 * ty + 1][d];
        const float a2 = featS[4 * ty + 2][d];
        const float a3 = featS[4 * ty + 3][d];
        const float4 wr = *(const float4*)&Wlds[d][4 * tx];
        acc[0][0] = fmaf(a0, wr.x, acc[0][0]); acc[0][1] = fmaf(a0, wr.y, acc[0][1]);
        acc[0][2] = fmaf(a0, wr.z, acc[0][2]); acc[0][3] = fmaf(a0, wr.w, acc[0][3]);
        acc[1][0] = fmaf(a1, wr.x, acc[1][0]); acc[1][1] = fmaf(a1, wr.y, acc[1][1]);
        acc[1][2] = fmaf(a1, wr.z, acc[1][2]); acc[1][3] = fmaf(a1, wr.w, acc[1][3]);
        acc[2][0] = fmaf(a2, wr.x, acc[2][0]); acc[2][1] = fmaf(a2, wr.y, acc[2][1]);
        acc[2][2] = fmaf(a2, wr.z, acc[2][2]); acc[2][3] = fmaf(a2, wr.w, acc[2][3]);
        acc[3][0] = fmaf(a3, wr.x, acc[3][0]); acc[3][1] = fmaf(a3, wr.y, acc[3][1]);
        acc[3][2] = fmaf(a3, wr.z, acc[3][2]); acc[3][3] = fmaf(a3, wr.w, acc[3][3]);
    }
    #pragma unroll
    for (int j = 0; j < 4; ++j) {
        const int n = base + 4 * ty + j;
        if (n < N) {
            float4 o; o.x = acc[j][0]; o.y = acc[j][1]; o.z = acc[j][2]; o.w = acc[j][3];
            *(float4*)&out[(size_t)n * 64 + 4 * tx] = o;
        }
    }
}

extern "C" void kernel_launch(void* const* d_in, const int* in_sizes, int n_in,
                              void* d_out, int out_size, void* d_ws, size_t ws_size,
                              hipStream_t stream) {
    const float* values = (const float*)d_in[0];
    const float* p      = (const float*)d_in[1];
    const float* W      = (const float*)d_in[2];
    const float* b      = (const float*)d_in[3];
    const int*   feats  = (const int*)d_in[4];
    const int*   vidx   = (const int*)d_in[5];
    float* out = (float*)d_out;

    const int N  = in_sizes[5];
    const int KD = in_sizes[0];            // K * 64
    const int nblocks = (N + 63) / 64;

    const size_t val_bytes = (size_t)KD * 2;
    const size_t need      = val_bytes + 8192;
    if (ws_size >= need) {
        unsigned* valbf = (unsigned*)d_ws;
        uint4*    wfrag = (uint4*)((char*)d_ws + val_bytes);
        const int n8  = KD / 8;
        const int nvb = (n8 + TPB - 1) / TPB;
        cvt_inputs<<<nvb + 1, TPB, 0, stream>>>(
            (const float4*)values, (uint4*)valbf, n8, W, wfrag, nvb);
        fused_embed_proj_mfma<<<nblocks, TPB, 0, stream>>>(
            valbf, p, wfrag, b, feats, vidx, out, N);
    } else {
        fused_embed_proj_fp32<<<nblocks, TPB, 0, stream>>>(
            values, p, W, b, feats, vidx, out, N);
    }
}